// Round 4
// baseline (118.171 us; speedup 1.0000x reference)
//
#include <hip/hip_runtime.h>
#include <hip/hip_bf16.h>
#include <math.h>

#define NN 4096
#define HH 256
#define G3 768
#define NHEADS 3
#define MAXE 128
#define ALPHA 0.2f

typedef __bf16 bf16;
typedef __attribute__((ext_vector_type(2))) __bf16 bf16x2;
typedef __attribute__((ext_vector_type(4))) __bf16 bf16x4;
typedef __attribute__((ext_vector_type(8))) __bf16 bf16x8;
typedef __attribute__((ext_vector_type(4))) float f32x4;

__device__ __forceinline__ void async_copy16(void* lds, const void* g) {
    __builtin_amdgcn_global_load_lds((const __attribute__((address_space(1))) void*)g,
                                     (__attribute__((address_space(3))) void*)lds, 16, 0, 0);
}

__device__ inline float lrelu(float x) { return x > 0.f ? x : ALPHA * x; }
__device__ inline float sigm(float x) { return 1.f / (1.f + __expf(-x)); }

// ================= prep: all converts + transposes + gat_c in one kernel =================
__global__ __launch_bounds__(256) void prep_k(
    const float* __restrict__ h,
    const float* __restrict__ eWih, const float* __restrict__ eWhh,
    const float* __restrict__ nWih, const float* __restrict__ nWhh,
    const float* __restrict__ gat_W, const float* __restrict__ gat_a,
    bf16* __restrict__ hb,
    bf16* __restrict__ Weib, bf16* __restrict__ Wehb,
    bf16* __restrict__ Wnib, bf16* __restrict__ Wnhb,
    bf16* __restrict__ Wtb, float* __restrict__ c0, float* __restrict__ c1) {
    __shared__ float tile[32][33];
    __shared__ float a_s[512];
    int b = blockIdx.x, t = threadIdx.x;
    if (b < 1024) {
        int idx = b * 256 + t;
        float4 v = *(const float4*)(h + (size_t)idx * 4);
        bf16x4 o = {(bf16)v.x, (bf16)v.y, (bf16)v.z, (bf16)v.w};
        *(bf16x4*)(hb + (size_t)idx * 4) = o;
    } else if (b < 1792) {
        int w = (b - 1024) / 192;
        int idx = ((b - 1024) % 192) * 256 + t;
        const float* in = w == 0 ? eWih : (w == 1 ? eWhh : (w == 2 ? nWih : nWhh));
        bf16* outp = w == 0 ? Weib : (w == 1 ? Wehb : (w == 2 ? Wnib : Wnhb));
        float4 v = *(const float4*)(in + (size_t)idx * 4);
        bf16x4 o = {(bf16)v.x, (bf16)v.y, (bf16)v.z, (bf16)v.w};
        *(bf16x4*)(outp + (size_t)idx * 4) = o;
    } else if (b < 1984) {
        int b2 = b - 1792;
        int hd = b2 >> 6, tl = b2 & 63;
        int k0 = (tl >> 3) * 32, n0 = (tl & 7) * 32;
        int tx = t % 32, ty = t / 32;
        const float* Wh = gat_W + (size_t)hd * HH * HH;
        for (int r = ty; r < 32; r += 8) tile[r][tx] = Wh[(size_t)(k0 + r) * HH + n0 + tx];
        __syncthreads();
        bf16* Wth = Wtb + (size_t)hd * HH * HH;
        for (int r = ty; r < 32; r += 8) Wth[(size_t)(n0 + r) * HH + k0 + tx] = (bf16)tile[tx][r];
    } else {
        int hd = b - 1984;
        a_s[t] = gat_a[(size_t)hd * 512 + t];
        a_s[t + 256] = gat_a[(size_t)hd * 512 + 256 + t];
        __syncthreads();
        const float* Wr = gat_W + (size_t)hd * HH * HH + (size_t)t * HH;
        float s0 = 0.f, s1 = 0.f;
        for (int c = 0; c < HH; c++) {
            float w = Wr[c];
            s0 += w * a_s[c];
            s1 += w * a_s[256 + c];
        }
        c0[hd * HH + t] = s0;
        c1[hd * HH + t] = s1;
    }
}

// ================= merged adjacency scan (MLP-optimized) =================
// grid (NN, 2): y=0 node (gather + nsup + fused gat_e), y=1 edge (CSR + de)
__global__ __launch_bounds__(256) void scan_k(
    const float* __restrict__ node_adj, const float* __restrict__ edge_adj,
    const float* __restrict__ h,
    const float* __restrict__ c0, const float* __restrict__ c1,
    bf16* __restrict__ nsupb, float* __restrict__ dn, float* __restrict__ de,
    float* __restrict__ ep, float* __restrict__ em,
    int* __restrict__ csr_cols, int* __restrict__ csr_nnz) {
    int i = blockIdx.x, t = threadIdx.x;
    int lane = t & 63, wid = t >> 6;
    __shared__ int cnt;
    __shared__ int cols[256];
    __shared__ float part[6][4];
    if (t == 0) cnt = 0;
    __syncthreads();
    bool node = (blockIdx.y == 0);
    const float* adj = node ? node_adj : edge_adj;
    const float* row = adj + (size_t)i * NN;

    // prefetch entire row slice: 4 independent float4 loads in flight
    float4 v[4];
#pragma unroll
    for (int it = 0; it < 4; it++) v[it] = *(const float4*)(row + t * 4 + it * 1024);

    // deterministic diagonal write (thread owning element i)
    if (t == ((i & 1023) >> 2)) {
        float vv[4] = {v[i >> 10].x, v[i >> 10].y, v[i >> 10].z, v[i >> 10].w};
        (node ? dn : de)[i] = vv[i & 3];
    }

#pragma unroll
    for (int it = 0; it < 4; it++) {
        float vv[4] = {v[it].x, v[it].y, v[it].z, v[it].w};
        bool any = (vv[0] != 0.f) | (vv[1] != 0.f) | (vv[2] != 0.f) | (vv[3] != 0.f);
        if (any) {
#pragma unroll
            for (int e = 0; e < 4; e++) {
                int j = t * 4 + it * 1024 + e;
                float a = vv[e];
                if (a != 0.0f && j != i) {
                    int s = atomicAdd(&cnt, 1);
                    if (s < 256) cols[s] = (a > 0.0f) ? (j + 1) : -(j + 1);
                }
            }
        }
    }
    __syncthreads();
    if (node) {
        int n = cnt < 256 ? cnt : 256;
        float accp = 0.f, accm = 0.f;
#pragma unroll 4
        for (int k = 0; k < n; k++) {
            int c = cols[k];
            int j = (c > 0 ? c : -c) - 1;
            float hv = h[(size_t)j * HH + t];
            if (c > 0) accp += hv; else accm += hv;
        }
        nsupb[(size_t)i * HH + t] = (bf16)(accp - accm);
        // fused gat_e: 6 block-dot-products against c0/c1
        float u[6];
#pragma unroll
        for (int hd = 0; hd < NHEADS; hd++) {
            float a0 = c0[hd * HH + t], a1 = c1[hd * HH + t];
            u[hd * 2]     = accp * a0 + accm * a1;
            u[hd * 2 + 1] = accm * a0 + accp * a1;
        }
#pragma unroll
        for (int vv = 0; vv < 6; vv++)
#pragma unroll
            for (int off = 32; off; off >>= 1) u[vv] += __shfl_xor(u[vv], off);
        if (lane == 0)
#pragma unroll
            for (int vv = 0; vv < 6; vv++) part[vv][wid] = u[vv];
        __syncthreads();
        if (t < 6) {
            float s = part[t][0] + part[t][1] + part[t][2] + part[t][3];
            int hd = t >> 1;
            ((t & 1) == 0 ? ep : em)[(size_t)hd * NN + i] = lrelu(s);
        }
    } else {
        int n = cnt < MAXE ? cnt : MAXE;
        if (t == 0) csr_nnz[i] = n;
        for (int k = t; k < n; k += 256) csr_cols[(size_t)i * MAXE + k] = cols[k];
    }
}

// ================= bf16 MFMA GEMM (m97 structure), z-batched up to 3 =================
__global__ __launch_bounds__(256) void gemm_bt(
    const bf16* __restrict__ A0, const bf16* __restrict__ A1, const bf16* __restrict__ A2,
    const bf16* __restrict__ B0, const bf16* __restrict__ B1, const bf16* __restrict__ B2,
    bf16* __restrict__ C0, bf16* __restrict__ C1, bf16* __restrict__ C2) {
    __shared__ bf16 a_s[128 * 32];
    __shared__ bf16 b_s[128 * 32];
    int z = blockIdx.z;
    const bf16* A = z == 0 ? A0 : (z == 1 ? A1 : A2);
    const bf16* Bt = z == 0 ? B0 : (z == 1 ? B1 : B2);
    bf16* C = z == 0 ? C0 : (z == 1 ? C1 : C2);

    int tid = threadIdx.x;
    int lane = tid & 63, wid = tid >> 6;
    int wr = (wid >> 1) * 64, wc = (wid & 1) * 64;
    int i0 = blockIdx.x * 128;
    int c0n = blockIdx.y * 128;

    f32x4 acc[4][4] = {};
    int kq = (lane >> 4) * 8;

    for (int k0 = 0; k0 < 256; k0 += 32) {
        __syncthreads();
#pragma unroll
        for (int it = 0; it < 2; it++) {
            int ch = it * 256 + tid;
            int r = ch >> 2, c16 = ch & 3;
            async_copy16(&a_s[ch * 8], A + (size_t)(i0 + r) * 256 + k0 + c16 * 8);
            async_copy16(&b_s[ch * 8], Bt + (size_t)(c0n + r) * 256 + k0 + c16 * 8);
        }
        __syncthreads();
        bf16x8 af[4], bf[4];
#pragma unroll
        for (int m = 0; m < 4; m++) af[m] = *(const bf16x8*)&a_s[(wr + m * 16 + (lane & 15)) * 32 + kq];
#pragma unroll
        for (int n = 0; n < 4; n++) bf[n] = *(const bf16x8*)&b_s[(wc + n * 16 + (lane & 15)) * 32 + kq];
#pragma unroll
        for (int m = 0; m < 4; m++)
#pragma unroll
            for (int n = 0; n < 4; n++)
                acc[m][n] = __builtin_amdgcn_mfma_f32_16x16x32_bf16(af[m], bf[n], acc[m][n], 0, 0, 0);
    }
#pragma unroll
    for (int m = 0; m < 4; m++) {
#pragma unroll
        for (int n = 0; n < 4; n++) {
            int row = i0 + wr + m * 16 + (lane >> 4) * 4;
            int col = c0n + wc + n * 16 + (lane & 15);
#pragma unroll
            for (int j = 0; j < 4; j++)
                C[(size_t)(row + j) * G3 + col] = (bf16)acc[m][n][j];
        }
    }
}

// ================= GAT sparse output =================
__global__ __launch_bounds__(256) void gat_out(
    const int* __restrict__ csr_cols, const int* __restrict__ csr_nnz,
    const float* __restrict__ ep, const float* __restrict__ em,
    const bf16* __restrict__ hWb2, bf16* __restrict__ esupb) {
    int i = blockIdx.x, t = threadIdx.x;
    __shared__ int cols_s[MAXE];
    __shared__ int js[MAXE];
    __shared__ float w_s[NHEADS][MAXE];
    int n = csr_nnz[i];
    if (t < MAXE && t < n) {
        int c = csr_cols[(size_t)i * MAXE + t];
        cols_s[t] = c;
        js[t] = (c > 0 ? c : -c) - 1;
    }
    __syncthreads();
    int wid = t >> 6, lane = t & 63;
    if (wid < NHEADS) {
        int hd = wid;
        const float* eph = ep + (size_t)hd * NN;
        const float* emh = em + (size_t)hd * NN;
        float v0 = -1e30f, v1 = -1e30f;
        if (lane < n)      { int c = cols_s[lane];      v0 = c > 0 ? eph[js[lane]]      : emh[js[lane]]; }
        if (lane + 64 < n) { int c = cols_s[lane + 64]; v1 = c > 0 ? eph[js[lane + 64]] : emh[js[lane + 64]]; }
        float mx = fmaxf(v0, v1);
#pragma unroll
        for (int off = 32; off; off >>= 1) mx = fmaxf(mx, __shfl_xor(mx, off));
        float w0 = (lane < n) ? __expf(v0 - mx) : 0.f;
        float w1 = (lane + 64 < n) ? __expf(v1 - mx) : 0.f;
        float s = w0 + w1;
#pragma unroll
        for (int off = 32; off; off >>= 1) s += __shfl_xor(s, off);
        float inv = 1.f / s;
        if (lane < n)      w_s[hd][lane]      = (cols_s[lane] > 0 ? w0 : -w0) * inv;
        if (lane + 64 < n) w_s[hd][lane + 64] = (cols_s[lane + 64] > 0 ? w1 : -w1) * inv;
    }
    __syncthreads();
    float acc = 0.f;
#pragma unroll
    for (int hd = 0; hd < NHEADS; hd++) {
        const bf16* base = hWb2 + (size_t)hd * HH + t;
#pragma unroll 4
        for (int k = 0; k < n; k++)
            acc += w_s[hd][k] * (float)base[(size_t)js[k] * G3];
    }
    esupb[(size_t)i * HH + t] = (bf16)(acc * (1.f / 3.f));
}

// ================= both GRU cells + final combine, writes d_out =================
__global__ __launch_bounds__(256) void gru_both(
    const bf16* __restrict__ gie, const bf16* __restrict__ ghe,
    const bf16* __restrict__ gin, const bf16* __restrict__ ghn,
    const float* __restrict__ ebih, const float* __restrict__ ebhh,
    const float* __restrict__ nbih, const float* __restrict__ nbhh,
    const float* __restrict__ h, const float* __restrict__ dnv, const float* __restrict__ dev,
    float* __restrict__ out) {
    int sub = threadIdx.x >> 7, tc = threadIdx.x & 127;
    int i = blockIdx.x * 2 + sub;
    int c = tc * 2;
    size_t gb = (size_t)i * G3;
    float2 hv = *(const float2*)(h + (size_t)i * HH + c);
    float De = dev[i], Dn = dnv[i];

#define LD2(p, off) (*(const bf16x2*)((p) + gb + (off) + c))
#define BI2(p, off) (*(const float2*)((p) + (off) + c))
    bf16x2 eir = LD2(gie, 0), eiz = LD2(gie, 256), ein = LD2(gie, 512);
    bf16x2 ehr = LD2(ghe, 0), ehz = LD2(ghe, 256), ehn = LD2(ghe, 512);
    bf16x2 nir = LD2(gin, 0), niz = LD2(gin, 256), nin = LD2(gin, 512);
    bf16x2 nhr = LD2(ghn, 0), nhz = LD2(ghn, 256), nhn = LD2(ghn, 512);
    float2 ebr = BI2(ebih, 0), ebz = BI2(ebih, 256), ebn = BI2(ebih, 512);
    float2 eb2r = BI2(ebhh, 0), eb2z = BI2(ebhh, 256), eb2n = BI2(ebhh, 512);
    float2 nbr = BI2(nbih, 0), nbz = BI2(nbih, 256), nbn = BI2(nbih, 512);
    float2 nb2r = BI2(nbhh, 0), nb2z = BI2(nbhh, 256), nb2n = BI2(nbhh, 512);
#undef LD2
#undef BI2

    float res[2];
#pragma unroll
    for (int j = 0; j < 2; j++) {
        float hj = j == 0 ? hv.x : hv.y;
        float r = sigm(((float)eir[j] + (j ? ebr.y : ebr.x)) + ((float)ehr[j] + (j ? eb2r.y : eb2r.x)));
        float z = sigm(((float)eiz[j] + (j ? ebz.y : ebz.x)) + ((float)ehz[j] + (j ? eb2z.y : eb2z.x)));
        float nv = tanhf(((float)ein[j] + (j ? ebn.y : ebn.x)) + r * ((float)ehn[j] + (j ? eb2n.y : eb2n.x)));
        float eo = (1.f - z) * nv + z * hj;
        float r2 = sigm(((float)nir[j] + (j ? nbr.y : nbr.x)) + ((float)nhr[j] + (j ? nb2r.y : nb2r.x)));
        float z2 = sigm(((float)niz[j] + (j ? nbz.y : nbz.x)) + ((float)nhz[j] + (j ? nb2z.y : nb2z.x)));
        float nv2 = tanhf(((float)nin[j] + (j ? nbn.y : nbn.x)) + r2 * ((float)nhn[j] + (j ? nb2n.y : nb2n.x)));
        float no = (1.f - z2) * nv2 + z2 * hj;
        res[j] = De * eo + Dn * no;
    }
    *(float2*)(out + (size_t)i * HH + c) = make_float2(res[0], res[1]);
}

extern "C" void kernel_launch(void* const* d_in, const int* in_sizes, int n_in,
                              void* d_out, int out_size, void* d_ws, size_t ws_size,
                              hipStream_t stream) {
    const float* h        = (const float*)d_in[0];
    const float* node_adj = (const float*)d_in[1];
    const float* edge_adj = (const float*)d_in[2];
    const float* gat_W    = (const float*)d_in[3];
    const float* gat_a    = (const float*)d_in[4];
    const float* e_Wih    = (const float*)d_in[5];
    const float* e_Whh    = (const float*)d_in[6];
    const float* e_bih    = (const float*)d_in[7];
    const float* e_bhh    = (const float*)d_in[8];
    const float* n_Wih    = (const float*)d_in[9];
    const float* n_Whh    = (const float*)d_in[10];
    const float* n_bih    = (const float*)d_in[11];
    const float* n_bhh    = (const float*)d_in[12];
    float* out = (float*)d_out;

    char* ws = (char*)d_ws;
    size_t off = 0;
    auto alloc = [&](size_t bytes) { char* p = ws + off; off += (bytes + 255) & ~(size_t)255; return p; };

    float* ep    = (float*)alloc((size_t)NHEADS * NN * 4);
    float* em    = (float*)alloc((size_t)NHEADS * NN * 4);
    float* c0    = (float*)alloc((size_t)NHEADS * HH * 4);
    float* c1    = (float*)alloc((size_t)NHEADS * HH * 4);
    float* dn    = (float*)alloc(NN * 4);
    float* de    = (float*)alloc(NN * 4);
    bf16*  hb    = (bf16*)alloc((size_t)NN * HH * 2);
    bf16*  nsupb = (bf16*)alloc((size_t)NN * HH * 2);
    bf16*  esupb = (bf16*)alloc((size_t)NN * HH * 2);
    bf16*  hWb2  = (bf16*)alloc((size_t)NN * G3 * 2);
    bf16*  gie   = (bf16*)alloc((size_t)NN * G3 * 2);
    bf16*  ghe   = (bf16*)alloc((size_t)NN * G3 * 2);
    bf16*  gin   = (bf16*)alloc((size_t)NN * G3 * 2);
    bf16*  ghn   = (bf16*)alloc((size_t)NN * G3 * 2);
    bf16*  Weib  = (bf16*)alloc((size_t)G3 * HH * 2);
    bf16*  Wehb  = (bf16*)alloc((size_t)G3 * HH * 2);
    bf16*  Wnib  = (bf16*)alloc((size_t)G3 * HH * 2);
    bf16*  Wnhb  = (bf16*)alloc((size_t)G3 * HH * 2);
    bf16*  Wtb   = (bf16*)alloc((size_t)NHEADS * HH * HH * 2);
    int*   csr_cols = (int*)alloc((size_t)NN * MAXE * 4);
    int*   csr_nnz  = (int*)alloc(NN * 4);

    dim3 b256(256);

    // 1. prep: converts + gat_W transpose + gat_c
    prep_k<<<1987, b256, 0, stream>>>(h, e_Wih, e_Whh, n_Wih, n_Whh, gat_W, gat_a,
                                      hb, Weib, Wehb, Wnib, Wnhb, Wtb, c0, c1);

    // 2. merged scans (node: gather+nsup+gat_e fused; edge: CSR)
    scan_k<<<dim3(NN, 2), b256, 0, stream>>>(node_adj, edge_adj, h, c0, c1,
                                             nsupb, dn, de, ep, em, csr_cols, csr_nnz);

    // 3. gemmA z=3: hW (3 heads concat N=768), gi_e, gh_e
    gemm_bt<<<dim3(NN / 128, G3 / 128, 3), b256, 0, stream>>>(
        hb, nsupb, hb, Wtb, Weib, Wehb, hWb2, gie, ghe);

    // 4. GAT sparse attention output
    gat_out<<<NN, b256, 0, stream>>>(csr_cols, csr_nnz, ep, em, hWb2, esupb);

    // 5. gemmB z=2: gi_n, gh_n
    gemm_bt<<<dim3(NN / 128, G3 / 128, 2), b256, 0, stream>>>(
        esupb, hb, hb, Wnib, Wnhb, Wnhb, gin, ghn, ghn);

    // 6. both GRUs + combine -> out
    gru_both<<<NN / 2, b256, 0, stream>>>(gie, ghe, gin, ghn,
                                          e_bih, e_bhh, n_bih, n_bhh,
                                          h, dn, de, out);
}

// Round 5
// 95.989 us; speedup vs baseline: 1.2311x; 1.2311x over previous
//
#include <hip/hip_runtime.h>
#include <hip/hip_bf16.h>
#include <math.h>

#define NN 4096
#define HH 256
#define G3 768
#define NHEADS 3
#define MAXE 128
#define ALPHA 0.2f

typedef __bf16 bf16;
typedef __attribute__((ext_vector_type(2))) __bf16 bf16x2;
typedef __attribute__((ext_vector_type(4))) __bf16 bf16x4;
typedef __attribute__((ext_vector_type(8))) __bf16 bf16x8;
typedef __attribute__((ext_vector_type(4))) float f32x4;

__device__ __forceinline__ void async_copy16(void* lds, const void* g) {
    __builtin_amdgcn_global_load_lds((const __attribute__((address_space(1))) void*)g,
                                     (__attribute__((address_space(3))) void*)lds, 16, 0, 0);
}

__device__ inline float lrelu(float x) { return x > 0.f ? x : ALPHA * x; }
__device__ inline float sigm(float x) { return 1.f / (1.f + __expf(-x)); }

// ================= prep: all converts + transposes + gat_c in one kernel =================
__global__ __launch_bounds__(256) void prep_k(
    const float* __restrict__ h,
    const float* __restrict__ eWih, const float* __restrict__ eWhh,
    const float* __restrict__ nWih, const float* __restrict__ nWhh,
    const float* __restrict__ gat_W, const float* __restrict__ gat_a,
    bf16* __restrict__ hb,
    bf16* __restrict__ Weib, bf16* __restrict__ Wehb,
    bf16* __restrict__ Wnib, bf16* __restrict__ Wnhb,
    bf16* __restrict__ Wtb, float* __restrict__ c0, float* __restrict__ c1) {
    __shared__ float tile[32][33];
    __shared__ float a_s[512];
    int b = blockIdx.x, t = threadIdx.x;
    if (b < 1024) {
        int idx = b * 256 + t;
        float4 v = *(const float4*)(h + (size_t)idx * 4);
        bf16x4 o = {(bf16)v.x, (bf16)v.y, (bf16)v.z, (bf16)v.w};
        *(bf16x4*)(hb + (size_t)idx * 4) = o;
    } else if (b < 1792) {
        int w = (b - 1024) / 192;
        int idx = ((b - 1024) % 192) * 256 + t;
        const float* in = w == 0 ? eWih : (w == 1 ? eWhh : (w == 2 ? nWih : nWhh));
        bf16* outp = w == 0 ? Weib : (w == 1 ? Wehb : (w == 2 ? Wnib : Wnhb));
        float4 v = *(const float4*)(in + (size_t)idx * 4);
        bf16x4 o = {(bf16)v.x, (bf16)v.y, (bf16)v.z, (bf16)v.w};
        *(bf16x4*)(outp + (size_t)idx * 4) = o;
    } else if (b < 1984) {
        int b2 = b - 1792;
        int hd = b2 >> 6, tl = b2 & 63;
        int k0 = (tl >> 3) * 32, n0 = (tl & 7) * 32;
        int tx = t % 32, ty = t / 32;
        const float* Wh = gat_W + (size_t)hd * HH * HH;
        for (int r = ty; r < 32; r += 8) tile[r][tx] = Wh[(size_t)(k0 + r) * HH + n0 + tx];
        __syncthreads();
        bf16* Wth = Wtb + (size_t)hd * HH * HH;
        for (int r = ty; r < 32; r += 8) Wth[(size_t)(n0 + r) * HH + k0 + tx] = (bf16)tile[tx][r];
    } else {
        int hd = b - 1984;
        a_s[t] = gat_a[(size_t)hd * 512 + t];
        a_s[t + 256] = gat_a[(size_t)hd * 512 + 256 + t];
        __syncthreads();
        const float* Wr = gat_W + (size_t)hd * HH * HH + (size_t)t * HH;
        float s0 = 0.f, s1 = 0.f;
        for (int c = 0; c < HH; c++) {
            float w = Wr[c];
            s0 += w * a_s[c];
            s1 += w * a_s[256 + c];
        }
        c0[hd * HH + t] = s0;
        c1[hd * HH + t] = s1;
    }
}

// ================= merged adjacency scan (named-register prefetch) =================
// grid (NN, 2): y=0 node (bf16 gather + nsup + fused gat_e), y=1 edge (CSR + de)
__global__ __launch_bounds__(256) void scan_k(
    const float* __restrict__ node_adj, const float* __restrict__ edge_adj,
    const bf16* __restrict__ hb,
    const float* __restrict__ c0, const float* __restrict__ c1,
    bf16* __restrict__ nsupb, float* __restrict__ dn, float* __restrict__ de,
    float* __restrict__ ep, float* __restrict__ em,
    int* __restrict__ csr_cols, int* __restrict__ csr_nnz) {
    int i = blockIdx.x, t = threadIdx.x;
    int lane = t & 63, wid = t >> 6;
    __shared__ int cnt;
    __shared__ int cols[256];
    __shared__ float part[6][4];
    if (t == 0) cnt = 0;
    __syncthreads();
    bool node = (blockIdx.y == 0);
    const float* row = (node ? node_adj : edge_adj) + (size_t)i * NN;

    // 4 independent float4 loads in flight — NAMED registers (no dynamic indexing)
    float4 v0 = *(const float4*)(row + t * 4);
    float4 v1 = *(const float4*)(row + t * 4 + 1024);
    float4 v2 = *(const float4*)(row + t * 4 + 2048);
    float4 v3 = *(const float4*)(row + t * 4 + 3072);

#define PELEM(A, J) { float a_ = (A); if (a_ != 0.0f) { \
        if ((J) == i) { (node ? dn : de)[i] = a_; } \
        else { int s_ = atomicAdd(&cnt, 1); if (s_ < 256) cols[s_] = (a_ > 0.0f) ? ((J) + 1) : -((J) + 1); } } }
#define PROC(V, OFS) { if ((V).x != 0.f || (V).y != 0.f || (V).z != 0.f || (V).w != 0.f) { \
        int jb_ = t * 4 + (OFS); \
        PELEM((V).x, jb_) PELEM((V).y, jb_ + 1) PELEM((V).z, jb_ + 2) PELEM((V).w, jb_ + 3) } }
    PROC(v0, 0)
    PROC(v1, 1024)
    PROC(v2, 2048)
    PROC(v3, 3072)
#undef PROC
#undef PELEM

    __syncthreads();
    if (node) {
        int n = cnt < 256 ? cnt : 256;
        float accp = 0.f, accm = 0.f;
#pragma unroll 4
        for (int k = 0; k < n; k++) {
            int c = cols[k];
            int j = (c > 0 ? c : -c) - 1;
            float hv = (float)hb[(size_t)j * HH + t];
            if (c > 0) accp += hv; else accm += hv;
        }
        nsupb[(size_t)i * HH + t] = (bf16)(accp - accm);
        // fused gat_e: 6 block-dot-products against c0/c1
        float u[6];
#pragma unroll
        for (int hd = 0; hd < NHEADS; hd++) {
            float a0 = c0[hd * HH + t], a1 = c1[hd * HH + t];
            u[hd * 2]     = accp * a0 + accm * a1;
            u[hd * 2 + 1] = accm * a0 + accp * a1;
        }
#pragma unroll
        for (int vv = 0; vv < 6; vv++)
#pragma unroll
            for (int off = 32; off; off >>= 1) u[vv] += __shfl_xor(u[vv], off);
        if (lane == 0)
#pragma unroll
            for (int vv = 0; vv < 6; vv++) part[vv][wid] = u[vv];
        __syncthreads();
        if (t < 6) {
            float s = part[t][0] + part[t][1] + part[t][2] + part[t][3];
            int hd = t >> 1;
            ((t & 1) == 0 ? ep : em)[(size_t)hd * NN + i] = lrelu(s);
        }
    } else {
        int n = cnt < MAXE ? cnt : MAXE;
        if (t == 0) csr_nnz[i] = n;
        for (int k = t; k < n; k += 256) csr_cols[(size_t)i * MAXE + k] = cols[k];
    }
}

// ================= bf16 MFMA GEMM (m97 structure), z-batched up to 3 =================
__global__ __launch_bounds__(256) void gemm_bt(
    const bf16* __restrict__ A0, const bf16* __restrict__ A1, const bf16* __restrict__ A2,
    const bf16* __restrict__ B0, const bf16* __restrict__ B1, const bf16* __restrict__ B2,
    bf16* __restrict__ C0, bf16* __restrict__ C1, bf16* __restrict__ C2) {
    __shared__ bf16 a_s[128 * 32];
    __shared__ bf16 b_s[128 * 32];
    int z = blockIdx.z;
    const bf16* A = z == 0 ? A0 : (z == 1 ? A1 : A2);
    const bf16* Bt = z == 0 ? B0 : (z == 1 ? B1 : B2);
    bf16* C = z == 0 ? C0 : (z == 1 ? C1 : C2);

    int tid = threadIdx.x;
    int lane = tid & 63, wid = tid >> 6;
    int wr = (wid >> 1) * 64, wc = (wid & 1) * 64;
    int i0 = blockIdx.x * 128;
    int c0n = blockIdx.y * 128;

    f32x4 acc[4][4] = {};
    int kq = (lane >> 4) * 8;

    for (int k0 = 0; k0 < 256; k0 += 32) {
        __syncthreads();
#pragma unroll
        for (int it = 0; it < 2; it++) {
            int ch = it * 256 + tid;
            int r = ch >> 2, c16 = ch & 3;
            async_copy16(&a_s[ch * 8], A + (size_t)(i0 + r) * 256 + k0 + c16 * 8);
            async_copy16(&b_s[ch * 8], Bt + (size_t)(c0n + r) * 256 + k0 + c16 * 8);
        }
        __syncthreads();
        bf16x8 af[4], bf[4];
#pragma unroll
        for (int m = 0; m < 4; m++) af[m] = *(const bf16x8*)&a_s[(wr + m * 16 + (lane & 15)) * 32 + kq];
#pragma unroll
        for (int n = 0; n < 4; n++) bf[n] = *(const bf16x8*)&b_s[(wc + n * 16 + (lane & 15)) * 32 + kq];
#pragma unroll
        for (int m = 0; m < 4; m++)
#pragma unroll
            for (int n = 0; n < 4; n++)
                acc[m][n] = __builtin_amdgcn_mfma_f32_16x16x32_bf16(af[m], bf[n], acc[m][n], 0, 0, 0);
    }
#pragma unroll
    for (int m = 0; m < 4; m++) {
#pragma unroll
        for (int n = 0; n < 4; n++) {
            int row = i0 + wr + m * 16 + (lane >> 4) * 4;
            int col = c0n + wc + n * 16 + (lane & 15);
#pragma unroll
            for (int j = 0; j < 4; j++)
                C[(size_t)(row + j) * G3 + col] = (bf16)acc[m][n][j];
        }
    }
}

// ================= GAT sparse output =================
__global__ __launch_bounds__(256) void gat_out(
    const int* __restrict__ csr_cols, const int* __restrict__ csr_nnz,
    const float* __restrict__ ep, const float* __restrict__ em,
    const bf16* __restrict__ hWb2, bf16* __restrict__ esupb) {
    int i = blockIdx.x, t = threadIdx.x;
    __shared__ int cols_s[MAXE];
    __shared__ int js[MAXE];
    __shared__ float w_s[NHEADS][MAXE];
    int n = csr_nnz[i];
    if (t < MAXE && t < n) {
        int c = csr_cols[(size_t)i * MAXE + t];
        cols_s[t] = c;
        js[t] = (c > 0 ? c : -c) - 1;
    }
    __syncthreads();
    int wid = t >> 6, lane = t & 63;
    if (wid < NHEADS) {
        int hd = wid;
        const float* eph = ep + (size_t)hd * NN;
        const float* emh = em + (size_t)hd * NN;
        float v0 = -1e30f, v1 = -1e30f;
        if (lane < n)      { int c = cols_s[lane];      v0 = c > 0 ? eph[js[lane]]      : emh[js[lane]]; }
        if (lane + 64 < n) { int c = cols_s[lane + 64]; v1 = c > 0 ? eph[js[lane + 64]] : emh[js[lane + 64]]; }
        float mx = fmaxf(v0, v1);
#pragma unroll
        for (int off = 32; off; off >>= 1) mx = fmaxf(mx, __shfl_xor(mx, off));
        float w0 = (lane < n) ? __expf(v0 - mx) : 0.f;
        float w1 = (lane + 64 < n) ? __expf(v1 - mx) : 0.f;
        float s = w0 + w1;
#pragma unroll
        for (int off = 32; off; off >>= 1) s += __shfl_xor(s, off);
        float inv = 1.f / s;
        if (lane < n)      w_s[hd][lane]      = (cols_s[lane] > 0 ? w0 : -w0) * inv;
        if (lane + 64 < n) w_s[hd][lane + 64] = (cols_s[lane + 64] > 0 ? w1 : -w1) * inv;
    }
    __syncthreads();
    float acc = 0.f;
#pragma unroll
    for (int hd = 0; hd < NHEADS; hd++) {
        const bf16* base = hWb2 + (size_t)hd * HH + t;
#pragma unroll 4
        for (int k = 0; k < n; k++)
            acc += w_s[hd][k] * (float)base[(size_t)js[k] * G3];
    }
    esupb[(size_t)i * HH + t] = (bf16)(acc * (1.f / 3.f));
}

// ================= both GRU cells + final combine, writes d_out =================
__global__ __launch_bounds__(256) void gru_both(
    const bf16* __restrict__ gie, const bf16* __restrict__ ghe,
    const bf16* __restrict__ gin, const bf16* __restrict__ ghn,
    const float* __restrict__ ebih, const float* __restrict__ ebhh,
    const float* __restrict__ nbih, const float* __restrict__ nbhh,
    const float* __restrict__ h, const float* __restrict__ dnv, const float* __restrict__ dev,
    float* __restrict__ out) {
    int sub = threadIdx.x >> 7, tc = threadIdx.x & 127;
    int i = blockIdx.x * 2 + sub;
    int c = tc * 2;
    size_t gb = (size_t)i * G3;
    float2 hv = *(const float2*)(h + (size_t)i * HH + c);
    float De = dev[i], Dn = dnv[i];

#define LD2(p, off) (*(const bf16x2*)((p) + gb + (off) + c))
#define BI2(p, off) (*(const float2*)((p) + (off) + c))
    bf16x2 eir = LD2(gie, 0), eiz = LD2(gie, 256), ein = LD2(gie, 512);
    bf16x2 ehr = LD2(ghe, 0), ehz = LD2(ghe, 256), ehn = LD2(ghe, 512);
    bf16x2 nir = LD2(gin, 0), niz = LD2(gin, 256), nin = LD2(gin, 512);
    bf16x2 nhr = LD2(ghn, 0), nhz = LD2(ghn, 256), nhn = LD2(ghn, 512);
    float2 ebr = BI2(ebih, 0), ebz = BI2(ebih, 256), ebn = BI2(ebih, 512);
    float2 eb2r = BI2(ebhh, 0), eb2z = BI2(ebhh, 256), eb2n = BI2(ebhh, 512);
    float2 nbr = BI2(nbih, 0), nbz = BI2(nbih, 256), nbn = BI2(nbih, 512);
    float2 nb2r = BI2(nbhh, 0), nb2z = BI2(nbhh, 256), nb2n = BI2(nbhh, 512);
#undef LD2
#undef BI2

    float res[2];
#pragma unroll
    for (int j = 0; j < 2; j++) {
        float hj = j == 0 ? hv.x : hv.y;
        float r = sigm(((float)eir[j] + (j ? ebr.y : ebr.x)) + ((float)ehr[j] + (j ? eb2r.y : eb2r.x)));
        float z = sigm(((float)eiz[j] + (j ? ebz.y : ebz.x)) + ((float)ehz[j] + (j ? eb2z.y : eb2z.x)));
        float nv = tanhf(((float)ein[j] + (j ? ebn.y : ebn.x)) + r * ((float)ehn[j] + (j ? eb2n.y : eb2n.x)));
        float eo = (1.f - z) * nv + z * hj;
        float r2 = sigm(((float)nir[j] + (j ? nbr.y : nbr.x)) + ((float)nhr[j] + (j ? nb2r.y : nb2r.x)));
        float z2 = sigm(((float)niz[j] + (j ? nbz.y : nbz.x)) + ((float)nhz[j] + (j ? nb2z.y : nb2z.x)));
        float nv2 = tanhf(((float)nin[j] + (j ? nbn.y : nbn.x)) + r2 * ((float)nhn[j] + (j ? nb2n.y : nb2n.x)));
        float no = (1.f - z2) * nv2 + z2 * hj;
        res[j] = De * eo + Dn * no;
    }
    *(float2*)(out + (size_t)i * HH + c) = make_float2(res[0], res[1]);
}

extern "C" void kernel_launch(void* const* d_in, const int* in_sizes, int n_in,
                              void* d_out, int out_size, void* d_ws, size_t ws_size,
                              hipStream_t stream) {
    const float* h        = (const float*)d_in[0];
    const float* node_adj = (const float*)d_in[1];
    const float* edge_adj = (const float*)d_in[2];
    const float* gat_W    = (const float*)d_in[3];
    const float* gat_a    = (const float*)d_in[4];
    const float* e_Wih    = (const float*)d_in[5];
    const float* e_Whh    = (const float*)d_in[6];
    const float* e_bih    = (const float*)d_in[7];
    const float* e_bhh    = (const float*)d_in[8];
    const float* n_Wih    = (const float*)d_in[9];
    const float* n_Whh    = (const float*)d_in[10];
    const float* n_bih    = (const float*)d_in[11];
    const float* n_bhh    = (const float*)d_in[12];
    float* out = (float*)d_out;

    char* ws = (char*)d_ws;
    size_t off = 0;
    auto alloc = [&](size_t bytes) { char* p = ws + off; off += (bytes + 255) & ~(size_t)255; return p; };

    float* ep    = (float*)alloc((size_t)NHEADS * NN * 4);
    float* em    = (float*)alloc((size_t)NHEADS * NN * 4);
    float* c0    = (float*)alloc((size_t)NHEADS * HH * 4);
    float* c1    = (float*)alloc((size_t)NHEADS * HH * 4);
    float* dn    = (float*)alloc(NN * 4);
    float* de    = (float*)alloc(NN * 4);
    bf16*  hb    = (bf16*)alloc((size_t)NN * HH * 2);
    bf16*  nsupb = (bf16*)alloc((size_t)NN * HH * 2);
    bf16*  esupb = (bf16*)alloc((size_t)NN * HH * 2);
    bf16*  hWb2  = (bf16*)alloc((size_t)NN * G3 * 2);
    bf16*  gie   = (bf16*)alloc((size_t)NN * G3 * 2);
    bf16*  ghe   = (bf16*)alloc((size_t)NN * G3 * 2);
    bf16*  gin   = (bf16*)alloc((size_t)NN * G3 * 2);
    bf16*  ghn   = (bf16*)alloc((size_t)NN * G3 * 2);
    bf16*  Weib  = (bf16*)alloc((size_t)G3 * HH * 2);
    bf16*  Wehb  = (bf16*)alloc((size_t)G3 * HH * 2);
    bf16*  Wnib  = (bf16*)alloc((size_t)G3 * HH * 2);
    bf16*  Wnhb  = (bf16*)alloc((size_t)G3 * HH * 2);
    bf16*  Wtb   = (bf16*)alloc((size_t)NHEADS * HH * HH * 2);
    int*   csr_cols = (int*)alloc((size_t)NN * MAXE * 4);
    int*   csr_nnz  = (int*)alloc(NN * 4);

    dim3 b256(256);

    // 1. prep: converts + gat_W transpose + gat_c
    prep_k<<<1987, b256, 0, stream>>>(h, e_Wih, e_Whh, n_Wih, n_Whh, gat_W, gat_a,
                                      hb, Weib, Wehb, Wnib, Wnhb, Wtb, c0, c1);

    // 2. merged scans (node: gather+nsup+gat_e fused; edge: CSR)
    scan_k<<<dim3(NN, 2), b256, 0, stream>>>(node_adj, edge_adj, hb, c0, c1,
                                             nsupb, dn, de, ep, em, csr_cols, csr_nnz);

    // 3. gemmA z=3: hW (3 heads concat N=768), gi_e, gh_e
    gemm_bt<<<dim3(NN / 128, G3 / 128, 3), b256, 0, stream>>>(
        hb, nsupb, hb, Wtb, Weib, Wehb, hWb2, gie, ghe);

    // 4. GAT sparse attention output
    gat_out<<<NN, b256, 0, stream>>>(csr_cols, csr_nnz, ep, em, hWb2, esupb);

    // 5. gemmB z=2: gi_n, gh_n
    gemm_bt<<<dim3(NN / 128, G3 / 128, 2), b256, 0, stream>>>(
        esupb, hb, hb, Wnib, Wnhb, Wnhb, gin, ghn, ghn);

    // 6. both GRUs + combine -> out
    gru_both<<<NN / 2, b256, 0, stream>>>(gie, ghe, gin, ghn,
                                          e_bih, e_bhh, n_bih, n_bhh,
                                          h, dn, de, out);
}

// Round 6
// 85.964 us; speedup vs baseline: 1.3747x; 1.1166x over previous
//
#include <hip/hip_runtime.h>
#include <hip/hip_bf16.h>
#include <math.h>

#define NN 4096
#define HH 256
#define G3 768
#define NHEADS 3
#define MAXE 128
#define ALPHA 0.2f

typedef __bf16 bf16;
typedef __attribute__((ext_vector_type(2))) __bf16 bf16x2;
typedef __attribute__((ext_vector_type(4))) __bf16 bf16x4;
typedef __attribute__((ext_vector_type(8))) __bf16 bf16x8;
typedef __attribute__((ext_vector_type(4))) float f32x4;

__device__ __forceinline__ void async_copy16(void* lds, const void* g) {
    __builtin_amdgcn_global_load_lds((const __attribute__((address_space(1))) void*)g,
                                     (__attribute__((address_space(3))) void*)lds, 16, 0, 0);
}

__device__ inline float lrelu(float x) { return x > 0.f ? x : ALPHA * x; }
__device__ inline float sigm(float x) { return 1.f / (1.f + __expf(-x)); }

// ================= prep: all converts + transposes + gat_c in one kernel =================
__global__ __launch_bounds__(256) void prep_k(
    const float* __restrict__ h,
    const float* __restrict__ eWih, const float* __restrict__ eWhh,
    const float* __restrict__ nWih, const float* __restrict__ nWhh,
    const float* __restrict__ gat_W, const float* __restrict__ gat_a,
    bf16* __restrict__ hb,
    bf16* __restrict__ Weib, bf16* __restrict__ Wehb,
    bf16* __restrict__ Wnib, bf16* __restrict__ Wnhb,
    bf16* __restrict__ Wtb, float* __restrict__ c0, float* __restrict__ c1) {
    __shared__ float tile[32][33];
    __shared__ float a_s[512];
    int b = blockIdx.x, t = threadIdx.x;
    if (b < 1024) {
        int idx = b * 256 + t;
        float4 v = *(const float4*)(h + (size_t)idx * 4);
        bf16x4 o = {(bf16)v.x, (bf16)v.y, (bf16)v.z, (bf16)v.w};
        *(bf16x4*)(hb + (size_t)idx * 4) = o;
    } else if (b < 1792) {
        int w = (b - 1024) / 192;
        int idx = ((b - 1024) % 192) * 256 + t;
        const float* in = w == 0 ? eWih : (w == 1 ? eWhh : (w == 2 ? nWih : nWhh));
        bf16* outp = w == 0 ? Weib : (w == 1 ? Wehb : (w == 2 ? Wnib : Wnhb));
        float4 v = *(const float4*)(in + (size_t)idx * 4);
        bf16x4 o = {(bf16)v.x, (bf16)v.y, (bf16)v.z, (bf16)v.w};
        *(bf16x4*)(outp + (size_t)idx * 4) = o;
    } else if (b < 1984) {
        int b2 = b - 1792;
        int hd = b2 >> 6, tl = b2 & 63;
        int k0 = (tl >> 3) * 32, n0 = (tl & 7) * 32;
        int tx = t % 32, ty = t / 32;
        const float* Wh = gat_W + (size_t)hd * HH * HH;
        for (int r = ty; r < 32; r += 8) tile[r][tx] = Wh[(size_t)(k0 + r) * HH + n0 + tx];
        __syncthreads();
        bf16* Wth = Wtb + (size_t)hd * HH * HH;
        for (int r = ty; r < 32; r += 8) Wth[(size_t)(n0 + r) * HH + k0 + tx] = (bf16)tile[tx][r];
    } else {
        int hd = b - 1984;
        a_s[t] = gat_a[(size_t)hd * 512 + t];
        a_s[t + 256] = gat_a[(size_t)hd * 512 + 256 + t];
        __syncthreads();
        const float* Wr = gat_W + (size_t)hd * HH * HH + (size_t)t * HH;
        f32x4 s0v = {}, s1v = {};
#pragma unroll 8
        for (int c4 = 0; c4 < 64; c4++) {
            f32x4 w = *(const f32x4*)(Wr + c4 * 4);
            f32x4 a0 = *(const f32x4*)(a_s + c4 * 4);
            f32x4 a1 = *(const f32x4*)(a_s + 256 + c4 * 4);
            s0v += w * a0;
            s1v += w * a1;
        }
        c0[hd * HH + t] = s0v[0] + s0v[1] + s0v[2] + s0v[3];
        c1[hd * HH + t] = s1v[0] + s1v[1] + s1v[2] + s1v[3];
    }
}

// ================= wave-per-row adjacency scan =================
// grid (NN/4, 2): 4 waves/block, each wave owns one row.
// y=0: node matrix (gather + nsup + fused gat_e). y=1: edge matrix (CSR + de).
__global__ __launch_bounds__(256) void scan_k(
    const float* __restrict__ node_adj, const float* __restrict__ edge_adj,
    const bf16* __restrict__ hb,
    const float* __restrict__ c0, const float* __restrict__ c1,
    bf16* __restrict__ nsupb, float* __restrict__ dn, float* __restrict__ de,
    float* __restrict__ ep, float* __restrict__ em,
    int* __restrict__ csr_cols, int* __restrict__ csr_nnz) {
    int t = threadIdx.x, lane = t & 63, wid = t >> 6;
    int i = blockIdx.x * 4 + wid;
    bool node = (blockIdx.y == 0);
    __shared__ int cnt[4];
    __shared__ int cols[4][MAXE];
    if (lane == 0) cnt[wid] = 0;
    __syncthreads();

    float* dia = node ? dn : de;
    const float* rp = (node ? node_adj : edge_adj) + (size_t)i * NN + lane * 4;

    // 16 independent 16-B loads in flight per lane (named registers)
    f32x4 v0  = *(const f32x4*)(rp);
    f32x4 v1  = *(const f32x4*)(rp + 256);
    f32x4 v2  = *(const f32x4*)(rp + 512);
    f32x4 v3  = *(const f32x4*)(rp + 768);
    f32x4 v4  = *(const f32x4*)(rp + 1024);
    f32x4 v5  = *(const f32x4*)(rp + 1280);
    f32x4 v6  = *(const f32x4*)(rp + 1536);
    f32x4 v7  = *(const f32x4*)(rp + 1792);
    f32x4 v8  = *(const f32x4*)(rp + 2048);
    f32x4 v9  = *(const f32x4*)(rp + 2304);
    f32x4 v10 = *(const f32x4*)(rp + 2560);
    f32x4 v11 = *(const f32x4*)(rp + 2816);
    f32x4 v12 = *(const f32x4*)(rp + 3072);
    f32x4 v13 = *(const f32x4*)(rp + 3328);
    f32x4 v14 = *(const f32x4*)(rp + 3584);
    f32x4 v15 = *(const f32x4*)(rp + 3840);

#define PEL(A, J) { float a_ = (A); if (a_ != 0.0f) { \
        if ((J) == i) { dia[i] = a_; } \
        else { int s_ = atomicAdd(&cnt[wid], 1); if (s_ < MAXE) cols[wid][s_] = (a_ > 0.0f) ? ((J) + 1) : -((J) + 1); } } }
#define PV(V, Q) { if ((V)[0] != 0.f || (V)[1] != 0.f || (V)[2] != 0.f || (V)[3] != 0.f) { \
        int jb_ = (Q) * 256 + lane * 4; \
        PEL((V)[0], jb_) PEL((V)[1], jb_ + 1) PEL((V)[2], jb_ + 2) PEL((V)[3], jb_ + 3) } }
    PV(v0, 0)  PV(v1, 1)  PV(v2, 2)  PV(v3, 3)
    PV(v4, 4)  PV(v5, 5)  PV(v6, 6)  PV(v7, 7)
    PV(v8, 8)  PV(v9, 9)  PV(v10, 10) PV(v11, 11)
    PV(v12, 12) PV(v13, 13) PV(v14, 14) PV(v15, 15)
#undef PV
#undef PEL

    __syncthreads();  // conservative: ensure wave's LDS writes/atomics drained
    int n = cnt[wid];
    if (n > MAXE) n = MAXE;

    if (node) {
        // lane owns h-columns lane*4..+3: vectorized bf16x4 gather
        f32x4 accp = {}, accm = {};
#pragma unroll 4
        for (int k = 0; k < n; k++) {
            int c = cols[wid][k];
            int j = (c > 0 ? c : -c) - 1;
            bf16x4 hv = *(const bf16x4*)(hb + (size_t)j * HH + lane * 4);
            f32x4 f = {(float)hv[0], (float)hv[1], (float)hv[2], (float)hv[3]};
            if (c > 0) accp += f; else accm += f;
        }
        f32x4 d = accp - accm;
        bf16x4 o = {(bf16)d[0], (bf16)d[1], (bf16)d[2], (bf16)d[3]};
        *(bf16x4*)(nsupb + (size_t)i * HH + lane * 4) = o;

        // fused gat_e: 6 wave-dot-products against c0/c1
        float u[6];
#pragma unroll
        for (int hd = 0; hd < NHEADS; hd++) {
            f32x4 a0 = *(const f32x4*)(c0 + hd * HH + lane * 4);
            f32x4 a1 = *(const f32x4*)(c1 + hd * HH + lane * 4);
            f32x4 up = accp * a0 + accm * a1;
            f32x4 um = accm * a0 + accp * a1;
            u[hd * 2]     = up[0] + up[1] + up[2] + up[3];
            u[hd * 2 + 1] = um[0] + um[1] + um[2] + um[3];
        }
#pragma unroll
        for (int vv = 0; vv < 6; vv++)
#pragma unroll
            for (int off = 32; off; off >>= 1) u[vv] += __shfl_xor(u[vv], off);
        if (lane == 0) {
#pragma unroll
            for (int hd = 0; hd < NHEADS; hd++) {
                ep[(size_t)hd * NN + i] = lrelu(u[hd * 2]);
                em[(size_t)hd * NN + i] = lrelu(u[hd * 2 + 1]);
            }
        }
    } else {
        if (lane == 0) csr_nnz[i] = n;
        for (int k = lane; k < n; k += 64) csr_cols[(size_t)i * MAXE + k] = cols[wid][k];
    }
}

// ================= bf16 MFMA GEMM (m97 structure), z-batched up to 3 =================
__global__ __launch_bounds__(256) void gemm_bt(
    const bf16* __restrict__ A0, const bf16* __restrict__ A1, const bf16* __restrict__ A2,
    const bf16* __restrict__ B0, const bf16* __restrict__ B1, const bf16* __restrict__ B2,
    bf16* __restrict__ C0, bf16* __restrict__ C1, bf16* __restrict__ C2) {
    __shared__ bf16 a_s[128 * 32];
    __shared__ bf16 b_s[128 * 32];
    int z = blockIdx.z;
    const bf16* A = z == 0 ? A0 : (z == 1 ? A1 : A2);
    const bf16* Bt = z == 0 ? B0 : (z == 1 ? B1 : B2);
    bf16* C = z == 0 ? C0 : (z == 1 ? C1 : C2);

    int tid = threadIdx.x;
    int lane = tid & 63, wid = tid >> 6;
    int wr = (wid >> 1) * 64, wc = (wid & 1) * 64;
    int i0 = blockIdx.x * 128;
    int c0n = blockIdx.y * 128;

    f32x4 acc[4][4] = {};
    int kq = (lane >> 4) * 8;

    for (int k0 = 0; k0 < 256; k0 += 32) {
        __syncthreads();
#pragma unroll
        for (int it = 0; it < 2; it++) {
            int ch = it * 256 + tid;
            int r = ch >> 2, c16 = ch & 3;
            async_copy16(&a_s[ch * 8], A + (size_t)(i0 + r) * 256 + k0 + c16 * 8);
            async_copy16(&b_s[ch * 8], Bt + (size_t)(c0n + r) * 256 + k0 + c16 * 8);
        }
        __syncthreads();
        bf16x8 af[4], bf[4];
#pragma unroll
        for (int m = 0; m < 4; m++) af[m] = *(const bf16x8*)&a_s[(wr + m * 16 + (lane & 15)) * 32 + kq];
#pragma unroll
        for (int n = 0; n < 4; n++) bf[n] = *(const bf16x8*)&b_s[(wc + n * 16 + (lane & 15)) * 32 + kq];
#pragma unroll
        for (int m = 0; m < 4; m++)
#pragma unroll
            for (int n = 0; n < 4; n++)
                acc[m][n] = __builtin_amdgcn_mfma_f32_16x16x32_bf16(af[m], bf[n], acc[m][n], 0, 0, 0);
    }
#pragma unroll
    for (int m = 0; m < 4; m++) {
#pragma unroll
        for (int n = 0; n < 4; n++) {
            int row = i0 + wr + m * 16 + (lane >> 4) * 4;
            int col = c0n + wc + n * 16 + (lane & 15);
#pragma unroll
            for (int j = 0; j < 4; j++)
                C[(size_t)(row + j) * G3 + col] = (bf16)acc[m][n][j];
        }
    }
}

// ================= GAT sparse output =================
// phase1: 3 waves -> per-head signed softmax weights. phase2: 192 threads = (head, colgroup),
// bf16x4 gathers, f32x4 accumulate; head-sum via LDS.
__global__ __launch_bounds__(256) void gat_out(
    const int* __restrict__ csr_cols, const int* __restrict__ csr_nnz,
    const float* __restrict__ ep, const float* __restrict__ em,
    const bf16* __restrict__ hWb2, bf16* __restrict__ esupb) {
    int i = blockIdx.x, t = threadIdx.x;
    __shared__ int cols_s[MAXE];
    __shared__ int js[MAXE];
    __shared__ float w_s[NHEADS][MAXE];
    __shared__ f32x4 sacc[NHEADS][64];
    int n = csr_nnz[i];
    if (t < n) {
        int c = csr_cols[(size_t)i * MAXE + t];
        cols_s[t] = c;
        js[t] = (c > 0 ? c : -c) - 1;
    }
    __syncthreads();
    int wid = t >> 6, lane = t & 63;
    if (wid < NHEADS) {
        int hd = wid;
        const float* eph = ep + (size_t)hd * NN;
        const float* emh = em + (size_t)hd * NN;
        float v0 = -1e30f, v1 = -1e30f;
        if (lane < n)      { int c = cols_s[lane];      v0 = c > 0 ? eph[js[lane]]      : emh[js[lane]]; }
        if (lane + 64 < n) { int c = cols_s[lane + 64]; v1 = c > 0 ? eph[js[lane + 64]] : emh[js[lane + 64]]; }
        float mx = fmaxf(v0, v1);
#pragma unroll
        for (int off = 32; off; off >>= 1) mx = fmaxf(mx, __shfl_xor(mx, off));
        float w0 = (lane < n) ? __expf(v0 - mx) : 0.f;
        float w1 = (lane + 64 < n) ? __expf(v1 - mx) : 0.f;
        float s = w0 + w1;
#pragma unroll
        for (int off = 32; off; off >>= 1) s += __shfl_xor(s, off);
        float inv = 1.f / s;
        if (lane < n)      w_s[hd][lane]      = (cols_s[lane] > 0 ? w0 : -w0) * inv;
        if (lane + 64 < n) w_s[hd][lane + 64] = (cols_s[lane + 64] > 0 ? w1 : -w1) * inv;
    }
    __syncthreads();
    if (t < 192) {
        int hd = t >> 6, g = t & 63;
        const bf16* base = hWb2 + (size_t)hd * HH + g * 4;
        f32x4 acc = {};
#pragma unroll 4
        for (int k = 0; k < n; k++) {
            float w = w_s[hd][k];
            bf16x4 hv = *(const bf16x4*)(base + (size_t)js[k] * G3);
            f32x4 f = {(float)hv[0], (float)hv[1], (float)hv[2], (float)hv[3]};
            acc += w * f;
        }
        sacc[hd][g] = acc;
    }
    __syncthreads();
    if (t < 64) {
        f32x4 s = (sacc[0][t] + sacc[1][t] + sacc[2][t]) * (1.f / 3.f);
        bf16x4 o = {(bf16)s[0], (bf16)s[1], (bf16)s[2], (bf16)s[3]};
        *(bf16x4*)(esupb + (size_t)i * HH + t * 4) = o;
    }
}

// ================= both GRU cells + final combine, writes d_out =================
__global__ __launch_bounds__(256) void gru_both(
    const bf16* __restrict__ gie, const bf16* __restrict__ ghe,
    const bf16* __restrict__ gin, const bf16* __restrict__ ghn,
    const float* __restrict__ ebih, const float* __restrict__ ebhh,
    const float* __restrict__ nbih, const float* __restrict__ nbhh,
    const float* __restrict__ h, const float* __restrict__ dnv, const float* __restrict__ dev,
    float* __restrict__ out) {
    int sub = threadIdx.x >> 7, tc = threadIdx.x & 127;
    int i = blockIdx.x * 2 + sub;
    int c = tc * 2;
    size_t gb = (size_t)i * G3;
    float2 hv = *(const float2*)(h + (size_t)i * HH + c);
    float De = dev[i], Dn = dnv[i];

#define LD2(p, off) (*(const bf16x2*)((p) + gb + (off) + c))
#define BI2(p, off) (*(const float2*)((p) + (off) + c))
    bf16x2 eir = LD2(gie, 0), eiz = LD2(gie, 256), ein = LD2(gie, 512);
    bf16x2 ehr = LD2(ghe, 0), ehz = LD2(ghe, 256), ehn = LD2(ghe, 512);
    bf16x2 nir = LD2(gin, 0), niz = LD2(gin, 256), nin = LD2(gin, 512);
    bf16x2 nhr = LD2(ghn, 0), nhz = LD2(ghn, 256), nhn = LD2(ghn, 512);
    float2 ebr = BI2(ebih, 0), ebz = BI2(ebih, 256), ebn = BI2(ebih, 512);
    float2 eb2r = BI2(ebhh, 0), eb2z = BI2(ebhh, 256), eb2n = BI2(ebhh, 512);
    float2 nbr = BI2(nbih, 0), nbz = BI2(nbih, 256), nbn = BI2(nbih, 512);
    float2 nb2r = BI2(nbhh, 0), nb2z = BI2(nbhh, 256), nb2n = BI2(nbhh, 512);
#undef LD2
#undef BI2

    float res[2];
#pragma unroll
    for (int j = 0; j < 2; j++) {
        float hj = j == 0 ? hv.x : hv.y;
        float r = sigm(((float)eir[j] + (j ? ebr.y : ebr.x)) + ((float)ehr[j] + (j ? eb2r.y : eb2r.x)));
        float z = sigm(((float)eiz[j] + (j ? ebz.y : ebz.x)) + ((float)ehz[j] + (j ? eb2z.y : eb2z.x)));
        float nv = tanhf(((float)ein[j] + (j ? ebn.y : ebn.x)) + r * ((float)ehn[j] + (j ? eb2n.y : eb2n.x)));
        float eo = (1.f - z) * nv + z * hj;
        float r2 = sigm(((float)nir[j] + (j ? nbr.y : nbr.x)) + ((float)nhr[j] + (j ? nb2r.y : nb2r.x)));
        float z2 = sigm(((float)niz[j] + (j ? nbz.y : nbz.x)) + ((float)nhz[j] + (j ? nb2z.y : nb2z.x)));
        float nv2 = tanhf(((float)nin[j] + (j ? nbn.y : nbn.x)) + r2 * ((float)nhn[j] + (j ? nb2n.y : nb2n.x)));
        float no = (1.f - z2) * nv2 + z2 * hj;
        res[j] = De * eo + Dn * no;
    }
    *(float2*)(out + (size_t)i * HH + c) = make_float2(res[0], res[1]);
}

extern "C" void kernel_launch(void* const* d_in, const int* in_sizes, int n_in,
                              void* d_out, int out_size, void* d_ws, size_t ws_size,
                              hipStream_t stream) {
    const float* h        = (const float*)d_in[0];
    const float* node_adj = (const float*)d_in[1];
    const float* edge_adj = (const float*)d_in[2];
    const float* gat_W    = (const float*)d_in[3];
    const float* gat_a    = (const float*)d_in[4];
    const float* e_Wih    = (const float*)d_in[5];
    const float* e_Whh    = (const float*)d_in[6];
    const float* e_bih    = (const float*)d_in[7];
    const float* e_bhh    = (const float*)d_in[8];
    const float* n_Wih    = (const float*)d_in[9];
    const float* n_Whh    = (const float*)d_in[10];
    const float* n_bih    = (const float*)d_in[11];
    const float* n_bhh    = (const float*)d_in[12];
    float* out = (float*)d_out;

    char* ws = (char*)d_ws;
    size_t off = 0;
    auto alloc = [&](size_t bytes) { char* p = ws + off; off += (bytes + 255) & ~(size_t)255; return p; };

    float* ep    = (float*)alloc((size_t)NHEADS * NN * 4);
    float* em    = (float*)alloc((size_t)NHEADS * NN * 4);
    float* c0    = (float*)alloc((size_t)NHEADS * HH * 4);
    float* c1    = (float*)alloc((size_t)NHEADS * HH * 4);
    float* dn    = (float*)alloc(NN * 4);
    float* de    = (float*)alloc(NN * 4);
    bf16*  hb    = (bf16*)alloc((size_t)NN * HH * 2);
    bf16*  nsupb = (bf16*)alloc((size_t)NN * HH * 2);
    bf16*  esupb = (bf16*)alloc((size_t)NN * HH * 2);
    bf16*  hWb2  = (bf16*)alloc((size_t)NN * G3 * 2);
    bf16*  gie   = (bf16*)alloc((size_t)NN * G3 * 2);
    bf16*  ghe   = (bf16*)alloc((size_t)NN * G3 * 2);
    bf16*  gin   = (bf16*)alloc((size_t)NN * G3 * 2);
    bf16*  ghn   = (bf16*)alloc((size_t)NN * G3 * 2);
    bf16*  Weib  = (bf16*)alloc((size_t)G3 * HH * 2);
    bf16*  Wehb  = (bf16*)alloc((size_t)G3 * HH * 2);
    bf16*  Wnib  = (bf16*)alloc((size_t)G3 * HH * 2);
    bf16*  Wnhb  = (bf16*)alloc((size_t)G3 * HH * 2);
    bf16*  Wtb   = (bf16*)alloc((size_t)NHEADS * HH * HH * 2);
    int*   csr_cols = (int*)alloc((size_t)NN * MAXE * 4);
    int*   csr_nnz  = (int*)alloc(NN * 4);

    dim3 b256(256);

    // 1. prep: converts + gat_W transpose + gat_c
    prep_k<<<1987, b256, 0, stream>>>(h, e_Wih, e_Whh, n_Wih, n_Whh, gat_W, gat_a,
                                      hb, Weib, Wehb, Wnib, Wnhb, Wtb, c0, c1);

    // 2. wave-per-row scans (node: gather+nsup+gat_e fused; edge: CSR)
    scan_k<<<dim3(NN / 4, 2), b256, 0, stream>>>(node_adj, edge_adj, hb, c0, c1,
                                                 nsupb, dn, de, ep, em, csr_cols, csr_nnz);

    // 3. gemmA z=3: hW (3 heads concat N=768), gi_e, gh_e
    gemm_bt<<<dim3(NN / 128, G3 / 128, 3), b256, 0, stream>>>(
        hb, nsupb, hb, Wtb, Weib, Wehb, hWb2, gie, ghe);

    // 4. GAT sparse attention output
    gat_out<<<NN, b256, 0, stream>>>(csr_cols, csr_nnz, ep, em, hWb2, esupb);

    // 5. gemmB z=2: gi_n, gh_n
    gemm_bt<<<dim3(NN / 128, G3 / 128, 2), b256, 0, stream>>>(
        esupb, hb, hb, Wnib, Wnhb, Wnhb, gin, ghn, ghn);

    // 6. both GRUs + combine -> out
    gru_both<<<NN / 2, b256, 0, stream>>>(gie, ghe, gin, ghn,
                                          e_bih, e_bhh, n_bih, n_bhh,
                                          h, dn, de, out);
}